// Round 9
// baseline (274.277 us; speedup 1.0000x reference)
//
#include <hip/hip_runtime.h>
#include <cstdint>
#include <cstddef>

// Static problem geometry
#define LEN_IN  21760
#define BATCH   2
#define MROWS   (BATCH * LEN_IN)   // 43520 = 64 * 680
// Levels: (128,128),(64,64),(32,32),(16,16); starts 0,16384,20480,21504

typedef _Float16 hv8 __attribute__((ext_vector_type(8)));   // 8 f16
typedef _Float16 hv2 __attribute__((ext_vector_type(2)));   // 2 f16 (half2)
typedef float    fv4 __attribute__((ext_vector_type(4)));

#define WAIT_LGKM0() __builtin_amdgcn_s_waitcnt(0xC07F)   // lgkmcnt(0) only
#define RAW_BARRIER() __builtin_amdgcn_s_barrier()

// ---------------------------------------------------------------------------
// Weight prep: coalesced 64x64 LDS transpose. K-major [K][N] -> [N][K] f16.
// Woff -> f16-split: rows [0,256) = hi, [256,512) = lo residual.
// WaT lands contiguously after WoffT2 so the fused GEMM sees B rows 512..639.
// ---------------------------------------------------------------------------
__global__ __launch_bounds__(256) void cvt_weights(
    const float* __restrict__ Wv, const float* __restrict__ Woff,
    const float* __restrict__ Wa, const float* __restrict__ Wo,
    _Float16* __restrict__ WvT, _Float16* __restrict__ WoffT2,
    _Float16* __restrict__ WaT, _Float16* __restrict__ WoT)
{
  __shared__ float t[64][65];
  const int id = blockIdx.x, tid = threadIdx.x;
  const int c = tid & 63, r4 = tid >> 6;

  const float* src; _Float16* dst; int N; bool split = false; int nt, kt;
  if (id < 16)      { src = Wv;   dst = WvT;    N = 256; nt = id & 3;        kt = id >> 2; }
  else if (id < 32) { src = Woff; dst = WoffT2; N = 256; nt = (id - 16) & 3; kt = (id - 16) >> 2; split = true; }
  else if (id < 40) { src = Wa;   dst = WaT;    N = 128; nt = (id - 32) & 1; kt = (id - 32) >> 1; }
  else              { src = Wo;   dst = WoT;    N = 256; nt = (id - 40) & 3; kt = (id - 40) >> 2; }
  const int nb = nt * 64, kb = kt * 64;

#pragma unroll
  for (int rr = 0; rr < 16; ++rr) {
    const int r = rr * 4 + r4;
    t[r][c] = src[(size_t)(kb + r) * N + nb + c];
  }
  __syncthreads();
#pragma unroll
  for (int rr = 0; rr < 16; ++rr) {
    const int r = rr * 4 + r4;
    const float v = t[c][r];
    const _Float16 h = (_Float16)v;
    dst[(size_t)(nb + r) * 256 + kb + c] = h;
    if (split)
      dst[(size_t)(256 + nb + r) * 256 + kb + c] = (_Float16)(v - (float)h);
  }
}

// ---------------------------------------------------------------------------
// value-GEMM body: 64x128 tile, LDS pipelined, A fp32 (cvt in regs),
// output f16 head planes. A register pipeline deepened to 4 (HBM ~900cy;
// the per-iter wait lands at B(k)'s in-order position, so A(k) issued 4
// iters ahead has ~1200cy of slack vs ~600 at 3-deep). B stays 2-deep (L2).
// Carve: As[2]=sh[0..2560),sh[2560..5120); Bs[2]=sh[5120..10240),sh[10240..15360).
// ---------------------------------------------------------------------------
__device__ __forceinline__ void value_body(
    const float* __restrict__ A32, const _Float16* __restrict__ Bt,
    const float* __restrict__ bias, _Float16* __restrict__ Cout,
    _Float16* sh, int bx, int by, int tid)
{
  _Float16* As[2] = {sh, sh + 2560};
  _Float16* Bs[2] = {sh + 5120, sh + 10240};

  const int lane = tid & 63, wave = tid >> 6;
  const int l15 = lane & 15, quad = lane >> 4;
  const int wc = wave * 32;
  const int rowBase = bx * 64;
  const int colBase = by * 128;
  const int rs = tid >> 2, ks = (tid & 3) * 8;

  float4 pa[4][2]; hv8 pb[2][2];

  auto issueA = [&](int it) {
    const int k0 = it * 32, s = it & 3;
    pa[s][0] = *(const float4*)&A32[(size_t)(rowBase + rs) * 256 + k0 + ks];
    pa[s][1] = *(const float4*)&A32[(size_t)(rowBase + rs) * 256 + k0 + ks + 4];
  };
  auto issueB = [&](int it) {
    const int k0 = it * 32, s = it & 1;
#pragma unroll
    for (int p = 0; p < 2; ++p)
      pb[s][p] = *(const hv8*)&Bt[(size_t)(colBase + p * 64 + rs) * 256 + k0 + ks];
  };

  // Preamble in need order (A 4-deep, B 2-deep)
  issueA(0); issueB(0); issueA(1); issueB(1); issueA(2); issueA(3);

  fv4 acc[4][2] = {};

#pragma unroll
  for (int it = 0; it < 8; ++it) {
    const int sb = it & 1, sa = it & 3;
    {
      const float4 f0 = pa[sa][0], f1 = pa[sa][1];
      const float fa[8] = {f0.x, f0.y, f0.z, f0.w, f1.x, f1.y, f1.z, f1.w};
      hv8 h;
#pragma unroll
      for (int e = 0; e < 8; ++e) h[e] = (_Float16)fa[e];
      *(hv8*)&As[sb][rs * 40 + ks] = h;
    }
#pragma unroll
    for (int p = 0; p < 2; ++p)
      *(hv8*)&Bs[sb][(p * 64 + rs) * 40 + ks] = pb[sb][p];
    if (it + 2 < 8) issueB(it + 2);   // need order: B first,
    if (it + 4 < 8) issueA(it + 4);   // then A (4-deep)
    WAIT_LGKM0();
    RAW_BARRIER();

    hv8 af[4];
#pragma unroll
    for (int i = 0; i < 4; ++i)
      af[i] = *(const hv8*)&As[sb][(i * 16 + l15) * 40 + quad * 8];
#pragma unroll
    for (int j = 0; j < 2; ++j) {
      const hv8 bf = *(const hv8*)&Bs[sb][(wc + j * 16 + l15) * 40 + quad * 8];
#pragma unroll
      for (int i = 0; i < 4; ++i)
        acc[i][j] = __builtin_amdgcn_mfma_f32_16x16x32_f16(af[i], bf, acc[i][j], 0, 0, 0);
    }
  }

#pragma unroll
  for (int j = 0; j < 2; ++j) {
    const int col = colBase + wc + j * 16 + l15;
    const float bj = bias[col];
#pragma unroll
    for (int i = 0; i < 4; ++i)
#pragma unroll
      for (int rg = 0; rg < 4; ++rg) {
        const int row = rowBase + i * 16 + quad * 4 + rg;
        const float v = acc[i][j][rg] + bj;
        const int n = (row >= LEN_IN) ? 1 : 0;
        const int pix = row - n * LEN_IN;
        const int m = col >> 5, d = col & 31;
        Cout[((size_t)(n * 8 + m) * LEN_IN + pix) * 32 + d] = (_Float16)v;
      }
  }
}

// ---------------------------------------------------------------------------
// offs/logits body: oy=0,1 -> offset coords (f16-split, 3 MFMAs);
// oy=2 -> logits (1 MFMA). A pipeline 4-deep (same rationale as value_body).
// Carve: Ash=sh[0..2560), Asl=sh[2560..5120), Bs=sh[5120..15360).
// ---------------------------------------------------------------------------
__device__ __forceinline__ void offs_body(
    const float* __restrict__ A, const _Float16* __restrict__ B2,
    const float* __restrict__ boff, const float* __restrict__ ba,
    const float* __restrict__ refpts,
    float* __restrict__ C, _Float16* __restrict__ logits16,
    _Float16* sh, int bx, int oy, int tid)
{
  _Float16* Ash = sh;
  _Float16* Asl = sh + 2560;
  _Float16* Bs  = sh + 5120;   // offs: rows 0-127 hi, 128-255 lo. logits: rows 0-127.

  const bool offs = (oy < 2);
  const int np = offs ? 4 : 2;
  const int lane = tid & 63, wave = tid >> 6;
  const int l15 = lane & 15, quad = lane >> 4;
  const int wc = wave * 32;
  const int rowBase = bx * 64;
  const int colBase = offs ? oy * 128 : 0;
  const int rs = tid >> 2, ks = (tid & 3) * 8;

  float4 pa[4][2]; hv8 pb[2][4];

  auto issueA = [&](int it) {
    const int k0 = it * 32, s = it & 3;
    pa[s][0] = *(const float4*)&A[(size_t)(rowBase + rs) * 256 + k0 + ks];
    pa[s][1] = *(const float4*)&A[(size_t)(rowBase + rs) * 256 + k0 + ks + 4];
  };
  auto issueB = [&](int it) {
    const int k0 = it * 32, s = it & 1;
#pragma unroll
    for (int p = 0; p < 4; ++p) {
      if (p >= np) break;
      const int grow = offs
          ? ((p < 2) ? (colBase + p * 64 + rs) : (256 + colBase + (p - 2) * 64 + rs))
          : (512 + p * 64 + rs);
      pb[s][p] = *(const hv8*)&B2[(size_t)grow * 256 + k0 + ks];
    }
  };

  issueA(0); issueB(0); issueA(1); issueB(1); issueA(2); issueA(3);

  fv4 acc[4][2] = {};

#pragma unroll
  for (int it = 0; it < 8; ++it) {
    const int sa = it & 3, s2 = it & 1;
    {
      const float4 f0 = pa[sa][0], f1 = pa[sa][1];
      const float fa[8] = {f0.x, f0.y, f0.z, f0.w, f1.x, f1.y, f1.z, f1.w};
      hv8 hh, ll;
#pragma unroll
      for (int e = 0; e < 8; ++e) {
        hh[e] = (_Float16)fa[e];
        ll[e] = (_Float16)(fa[e] - (float)hh[e]);
      }
      *(hv8*)&Ash[rs * 40 + ks] = hh;
      if (offs) *(hv8*)&Asl[rs * 40 + ks] = ll;
    }
#pragma unroll
    for (int p = 0; p < 4; ++p) {
      if (p >= np) break;
      *(hv8*)&Bs[(p * 64 + rs) * 40 + ks] = pb[s2][p];
    }
    if (it + 2 < 8) issueB(it + 2);
    if (it + 4 < 8) issueA(it + 4);
    WAIT_LGKM0();
    RAW_BARRIER();

    hv8 ah[4];
#pragma unroll
    for (int i = 0; i < 4; ++i)
      ah[i] = *(const hv8*)&Ash[(i * 16 + l15) * 40 + quad * 8];

    if (offs) {
      hv8 al[4];
#pragma unroll
      for (int i = 0; i < 4; ++i)
        al[i] = *(const hv8*)&Asl[(i * 16 + l15) * 40 + quad * 8];
#pragma unroll
      for (int j = 0; j < 2; ++j) {
        const hv8 bh = *(const hv8*)&Bs[(wc + j * 16 + l15) * 40 + quad * 8];
        const hv8 bl = *(const hv8*)&Bs[(128 + wc + j * 16 + l15) * 40 + quad * 8];
#pragma unroll
        for (int i = 0; i < 4; ++i) {
          acc[i][j] = __builtin_amdgcn_mfma_f32_16x16x32_f16(ah[i], bh, acc[i][j], 0, 0, 0);
          acc[i][j] = __builtin_amdgcn_mfma_f32_16x16x32_f16(ah[i], bl, acc[i][j], 0, 0, 0);
          acc[i][j] = __builtin_amdgcn_mfma_f32_16x16x32_f16(al[i], bh, acc[i][j], 0, 0, 0);
        }
      }
    } else {
#pragma unroll
      for (int j = 0; j < 2; ++j) {
        const hv8 bh = *(const hv8*)&Bs[(wc + j * 16 + l15) * 40 + quad * 8];
#pragma unroll
        for (int i = 0; i < 4; ++i)
          acc[i][j] = __builtin_amdgcn_mfma_f32_16x16x32_f16(ah[i], bh, acc[i][j], 0, 0, 0);
      }
    }
    WAIT_LGKM0();   // frag reads done before next iter overwrites (single buf)
    RAW_BARRIER();
  }

  if (offs) {
#pragma unroll
    for (int j = 0; j < 2; ++j) {
      const int c = colBase + wc + j * 16 + l15;
      const int xy = c & 1, l = (c >> 3) & 3;
      const float Wl = (float)(128 >> l);
      const float bj = boff[c];
#pragma unroll
      for (int i = 0; i < 4; ++i)
#pragma unroll
        for (int rg = 0; rg < 4; ++rg) {
          const int row = rowBase + i * 16 + quad * 4 + rg;
          const float ref = refpts[(size_t)row * 8 + l * 2 + xy];
          C[(size_t)row * 256 + c] = (acc[i][j][rg] + bj + ref) * Wl - 0.5f;
        }
    }
  } else {
#pragma unroll
    for (int j = 0; j < 2; ++j) {
      const int col = wc + j * 16 + l15;
      const float bj = ba[col];
#pragma unroll
      for (int i = 0; i < 4; ++i)
#pragma unroll
        for (int rg = 0; rg < 4; ++rg) {
          const int row = rowBase + i * 16 + quad * 4 + rg;
          logits16[(size_t)row * 128 + col] = (_Float16)(acc[i][j][rg] + bj);
        }
    }
  }
}

// ---------------------------------------------------------------------------
// MERGED front dispatch: OFFS blocks first (slower population: 2 barriers/
// iter, 24 MFMA/iter) so the dispatch tail is not dominated by them;
// value blocks follow. Same 30720 B LDS carve per body.
// ---------------------------------------------------------------------------
__global__ __launch_bounds__(256) void gemm_front(
    const float* __restrict__ flatten, const _Float16* __restrict__ WvT,
    const float* __restrict__ bv, _Float16* __restrict__ value16,
    const float* __restrict__ query, const _Float16* __restrict__ B2,
    const float* __restrict__ boff, const float* __restrict__ ba,
    const float* __restrict__ refpts,
    float* __restrict__ coords, _Float16* __restrict__ logits16)
{
  __shared__ _Float16 sh[15360];   // 30720 B, carved per body
  const int id = blockIdx.x, tid = threadIdx.x;
  if (id < 2040) {
    offs_body(query, B2, boff, ba, refpts, coords, logits16, sh,
              id % 680, id / 680, tid);
  } else {
    const int vid = id - 2040;
    value_body(flatten, WvT, bv, value16, sh, vid % 680, vid / 680, tid);
  }
}

// ---------------------------------------------------------------------------
// Final GEMM: A f16 (outp16), fp32 row-major out. A pipeline 4-deep.
// ---------------------------------------------------------------------------
__global__ __launch_bounds__(256) void gemm_final(
    const _Float16* __restrict__ A16, const _Float16* __restrict__ Bt,
    const float* __restrict__ bias, float* __restrict__ Cout)
{
  __shared__ _Float16 As[2][64 * 40];
  __shared__ _Float16 Bs[2][128 * 40];

  const int tid = threadIdx.x, lane = tid & 63, wave = tid >> 6;
  const int l15 = lane & 15, quad = lane >> 4;
  const int wc = wave * 32;
  const int rowBase = blockIdx.x * 64;
  const int colBase = blockIdx.y * 128;
  const int rs = tid >> 2, ks = (tid & 3) * 8;

  hv8 pa16[4]; hv8 pb[2][2];

  auto issueA = [&](int it) {
    const int k0 = it * 32, s = it & 3;
    pa16[s] = *(const hv8*)&A16[(size_t)(rowBase + rs) * 256 + k0 + ks];
  };
  auto issueB = [&](int it) {
    const int k0 = it * 32, s = it & 1;
#pragma unroll
    for (int p = 0; p < 2; ++p)
      pb[s][p] = *(const hv8*)&Bt[(size_t)(colBase + p * 64 + rs) * 256 + k0 + ks];
  };

  issueA(0); issueB(0); issueA(1); issueB(1); issueA(2); issueA(3);

  fv4 acc[4][2] = {};

#pragma unroll
  for (int it = 0; it < 8; ++it) {
    const int sb = it & 1, sa = it & 3;
    *(hv8*)&As[sb][rs * 40 + ks] = pa16[sa];
#pragma unroll
    for (int p = 0; p < 2; ++p)
      *(hv8*)&Bs[sb][(p * 64 + rs) * 40 + ks] = pb[sb][p];
    if (it + 2 < 8) issueB(it + 2);   // need order: B first,
    if (it + 4 < 8) issueA(it + 4);   // then A (4-deep)
    WAIT_LGKM0();
    RAW_BARRIER();

    hv8 af[4];
#pragma unroll
    for (int i = 0; i < 4; ++i)
      af[i] = *(const hv8*)&As[sb][(i * 16 + l15) * 40 + quad * 8];
#pragma unroll
    for (int j = 0; j < 2; ++j) {
      const hv8 bf = *(const hv8*)&Bs[sb][(wc + j * 16 + l15) * 40 + quad * 8];
#pragma unroll
      for (int i = 0; i < 4; ++i)
        acc[i][j] = __builtin_amdgcn_mfma_f32_16x16x32_f16(af[i], bf, acc[i][j], 0, 0, 0);
    }
  }

#pragma unroll
  for (int j = 0; j < 2; ++j) {
    const int col = colBase + wc + j * 16 + l15;
    const float bj = bias[col];
#pragma unroll
    for (int i = 0; i < 4; ++i)
#pragma unroll
      for (int rg = 0; rg < 4; ++rg) {
        const int row = rowBase + i * 16 + quad * 4 + rg;
        Cout[(size_t)row * 256 + col] = acc[i][j][rg] + bj;
      }
  }
}

// ---------------------------------------------------------------------------
// Sampler (R8: fdot2 corner-pair accumulate; gather-latency-bound ~70 us).
// ---------------------------------------------------------------------------
__global__ __launch_bounds__(256, 8) void sample_kernel(
    const _Float16* __restrict__ value16,  // head planes
    const float* __restrict__ coords,      // (B, LQ, 256) pixel coords
    const _Float16* __restrict__ logits16, // (B, LQ, 128)
    _Float16* __restrict__ outp16)         // (B, LQ, 256)
{
  __shared__ unsigned s_pair[4096];
  __shared__ float    s_attn[1024];

  const int tid = threadIdx.x;
  const int qBase = blockIdx.x * 8;

  if (tid < 64) {   // softmax per (q,m) over 16
    const hv8* lp = (const hv8*)&logits16[(size_t)(qBase + (tid >> 3)) * 128 + (tid & 7) * 16];
    const hv8 w0 = lp[0], w1 = lp[1];
    float w[16];
#pragma unroll
    for (int e = 0; e < 8; ++e) { w[e] = (float)w0[e]; w[8 + e] = (float)w1[e]; }
    float mx = w[0];
#pragma unroll
    for (int i = 1; i < 16; ++i) mx = fmaxf(mx, w[i]);
    float sum = 0.f;
#pragma unroll
    for (int i = 0; i < 16; ++i) { w[i] = expf(w[i] - mx); sum += w[i]; }
    const float inv = 1.f / sum;
#pragma unroll
    for (int p = 0; p < 16; ++p) s_attn[p * 64 + tid] = w[p] * inv;
  }
  __syncthreads();

#pragma unroll
  for (int k = 0; k < 4; ++k) {
    const int i = tid + 256 * k;
    const int p = i >> 6, q = (i >> 3) & 7, m = i & 7;
    const int l = p >> 2, pp = p & 3;
    const int qg = qBase + q;
    const float2 of = *(const float2*)&coords[(size_t)qg * 256 + ((m * 4 + l) * 4 + pp) * 2];
    const float aw = s_attn[i];
    const int W = 128 >> l;
    const int st = (l == 0) ? 0 : (l == 1) ? 16384 : (l == 2) ? 20480 : 21504;
    const float xf = floorf(of.x), yf = floorf(of.y);
    const int x0 = (int)xf, y0 = (int)yf;
    const float wx = of.x - xf, wy = of.y - yf;
    uint4 rec;
    unsigned* rp = &rec.x;
#pragma unroll
    for (int c = 0; c < 4; ++c) {
      const int dx = c & 1, dy = c >> 1;
      const int xi = x0 + dx, yi = y0 + dy;
      const bool valid = (xi >= 0) & (xi < W) & (yi >= 0) & (yi < W);
      const float w = (dx ? wx : 1.f - wx) * (dy ? wy : 1.f - wy) * aw;
      union { _Float16 h; unsigned short s; } pk;
      pk.h = (_Float16)w;
      const unsigned idx = (unsigned)(st + yi * W + xi);
      rp[c] = valid ? (idx | ((unsigned)pk.s << 16)) : 0u;
    }
    *(uint4*)&s_pair[i * 4] = rec;
  }
  __syncthreads();

  const int wave = tid >> 6, lane = tid & 63;
  const int qloc = wave * 2 + (lane >> 5);
  const int sub = lane & 31, m = sub >> 2, j = sub & 3;
  const int qg = qBase + qloc;
  const int n = (qg >= LEN_IN) ? 1 : 0;
  const char* base = (const char*)value16 + (size_t)(n * 8 + m) * LEN_IN * 64 + j * 16;
  const int lb = qloc * 8 + m;

  float acc8[8] = {0.f, 0.f, 0.f, 0.f, 0.f, 0.f, 0.f, 0.f};

  // Corner-pair accumulate: acc8[e] += wA*vA[e] + wB*vB[e] via fdot2.
  auto pair_acc = [&](unsigned uA, unsigned uB) {
    const hv8 vA = *(const hv8*)(base + (size_t)(uA & 32767u) * 64);
    const hv8 vB = *(const hv8*)(base + (size_t)(uB & 32767u) * 64);
    const unsigned wp = __builtin_amdgcn_perm(uB, uA, 0x07060302u);
    union { unsigned u; hv2 h; } w2; w2.u = wp;
    const unsigned* va = (const unsigned*)&vA;
    const unsigned* vb = (const unsigned*)&vB;
#pragma unroll
    for (int r = 0; r < 4; ++r) {
      union { unsigned u; hv2 h; } lo, hi;
      lo.u = __builtin_amdgcn_perm(vb[r], va[r], 0x05040100u);
      hi.u = __builtin_amdgcn_perm(vb[r], va[r], 0x07060302u);
      acc8[2 * r]     = __builtin_amdgcn_fdot2(w2.h, lo.h, acc8[2 * r],     false);
      acc8[2 * r + 1] = __builtin_amdgcn_fdot2(w2.h, hi.h, acc8[2 * r + 1], false);
    }
  };

#pragma unroll 4
  for (int p = 0; p < 16; ++p) {
    const uint4 u4 = *(const uint4*)&s_pair[(p * 64 + lb) * 4];
    pair_acc(u4.x, u4.y);
    pair_acc(u4.z, u4.w);
  }

  hv8 o;
#pragma unroll
  for (int e = 0; e < 8; ++e) o[e] = (_Float16)acc8[e];
  *(hv8*)&outp16[(size_t)qg * 256 + m * 32 + j * 8] = o;
}

// ---------------------------------------------------------------------------
extern "C" void kernel_launch(void* const* d_in, const int* in_sizes, int n_in,
                              void* d_out, int out_size, void* d_ws, size_t ws_size,
                              hipStream_t stream) {
  const float* query   = (const float*)d_in[0];
  const float* refpts  = (const float*)d_in[1];
  const float* flatten = (const float*)d_in[2];
  const float* Wv   = (const float*)d_in[5];
  const float* bv   = (const float*)d_in[6];
  const float* Woff = (const float*)d_in[7];
  const float* boff = (const float*)d_in[8];
  const float* Wa   = (const float*)d_in[9];
  const float* ba   = (const float*)d_in[10];
  const float* Wo   = (const float*)d_in[11];
  const float* bo   = (const float*)d_in[12];
  float* out = (float*)d_out;

  // Workspace (~101 MB): value16 | coords | logits16 | outp16 | weights
  const size_t NE = (size_t)MROWS * 256;            // 11,141,120
  _Float16* value16  = (_Float16*)d_ws;             // NE halves (head planes)
  float*    coords   = (float*)(value16 + NE);      // NE floats
  _Float16* logits16 = (_Float16*)(coords + NE);    // NE/2 halves
  _Float16* outp16   = logits16 + NE / 2;           // NE halves
  _Float16* WvT      = outp16 + NE;                 // 256*256
  _Float16* WoffT2   = WvT + 256 * 256;             // 512*256 (hi|lo)
  _Float16* WaT      = WoffT2 + 512 * 256;          // 128*256 (contig after WoffT2!)
  _Float16* WoT      = WaT + 128 * 256;             // 256*256

  const dim3 blk(256);
  const int mtiles = MROWS / 64;   // 680

  cvt_weights<<<dim3(56), blk, 0, stream>>>(Wv, Woff, Wa, Wo, WvT, WoffT2, WaT, WoT);

  // MERGED (offs first): coords/logits blocks 0..2039, value blocks 2040..3399
  gemm_front<<<dim3(3400), blk, 0, stream>>>(flatten, WvT, bv, value16,
                                             query, WoffT2, boff, ba, refpts,
                                             coords, logits16);

  // sampling -> out_pre (f16)
  sample_kernel<<<dim3(MROWS / 8), blk, 0, stream>>>(value16, coords, logits16, outp16);

  // out = out_pre @ Wo + bo (fp32 to d_out)
  gemm_final<<<dim3(mtiles, 2), blk, 0, stream>>>(outp16, WoT, bo, out);
}

// Round 10
// 272.814 us; speedup vs baseline: 1.0054x; 1.0054x over previous
//
#include <hip/hip_runtime.h>
#include <cstdint>
#include <cstddef>

// Static problem geometry
#define LEN_IN  21760
#define BATCH   2
#define MROWS   (BATCH * LEN_IN)   // 43520 = 64 * 680
// Levels: (128,128),(64,64),(32,32),(16,16); starts 0,16384,20480,21504

typedef _Float16 hv8 __attribute__((ext_vector_type(8)));   // 8 f16
typedef _Float16 hv2 __attribute__((ext_vector_type(2)));   // 2 f16 (half2)
typedef float    fv4 __attribute__((ext_vector_type(4)));

#define WAIT_LGKM0() __builtin_amdgcn_s_waitcnt(0xC07F)   // lgkmcnt(0) only
#define RAW_BARRIER() __builtin_amdgcn_s_barrier()

// global -> LDS direct (16B per lane; dest is wave-uniform base + lane*16)
__device__ __forceinline__ void glds16(const void* g, void* l) {
  __builtin_amdgcn_global_load_lds(
      (const __attribute__((address_space(1))) unsigned*)g,
      (__attribute__((address_space(3))) unsigned*)l, 16, 0, 0);
}

// ---------------------------------------------------------------------------
// Weight prep: coalesced 64x64 LDS transpose. K-major [K][N] -> [N][K] f16.
// Woff -> f16-split: rows [0,256) = hi, [256,512) = lo residual.
// WaT lands contiguously after WoffT2 so the fused GEMM sees B rows 512..639.
// ---------------------------------------------------------------------------
__global__ __launch_bounds__(256) void cvt_weights(
    const float* __restrict__ Wv, const float* __restrict__ Woff,
    const float* __restrict__ Wa, const float* __restrict__ Wo,
    _Float16* __restrict__ WvT, _Float16* __restrict__ WoffT2,
    _Float16* __restrict__ WaT, _Float16* __restrict__ WoT)
{
  __shared__ float t[64][65];
  const int id = blockIdx.x, tid = threadIdx.x;
  const int c = tid & 63, r4 = tid >> 6;

  const float* src; _Float16* dst; int N; bool split = false; int nt, kt;
  if (id < 16)      { src = Wv;   dst = WvT;    N = 256; nt = id & 3;        kt = id >> 2; }
  else if (id < 32) { src = Woff; dst = WoffT2; N = 256; nt = (id - 16) & 3; kt = (id - 16) >> 2; split = true; }
  else if (id < 40) { src = Wa;   dst = WaT;    N = 128; nt = (id - 32) & 1; kt = (id - 32) >> 1; }
  else              { src = Wo;   dst = WoT;    N = 256; nt = (id - 40) & 3; kt = (id - 40) >> 2; }
  const int nb = nt * 64, kb = kt * 64;

#pragma unroll
  for (int rr = 0; rr < 16; ++rr) {
    const int r = rr * 4 + r4;
    t[r][c] = src[(size_t)(kb + r) * N + nb + c];
  }
  __syncthreads();
#pragma unroll
  for (int rr = 0; rr < 16; ++rr) {
    const int r = rr * 4 + r4;
    const float v = t[c][r];
    const _Float16 h = (_Float16)v;
    dst[(size_t)(nb + r) * 256 + kb + c] = h;
    if (split)
      dst[(size_t)(256 + nb + r) * 256 + kb + c] = (_Float16)(v - (float)h);
  }
}

// ---------------------------------------------------------------------------
// value-GEMM body: 64x128 tile, LDS pipelined, A fp32 (cvt in regs),
// output f16 head planes. A reg pipeline 4-deep, B 2-deep.
// Carve: As[2]=sh[0..2560),sh[2560..5120); Bs[2]=sh[5120..10240),sh[10240..15360).
// ---------------------------------------------------------------------------
__device__ __forceinline__ void value_body(
    const float* __restrict__ A32, const _Float16* __restrict__ Bt,
    const float* __restrict__ bias, _Float16* __restrict__ Cout,
    _Float16* sh, int bx, int by, int tid)
{
  _Float16* As[2] = {sh, sh + 2560};
  _Float16* Bs[2] = {sh + 5120, sh + 10240};

  const int lane = tid & 63, wave = tid >> 6;
  const int l15 = lane & 15, quad = lane >> 4;
  const int wc = wave * 32;
  const int rowBase = bx * 64;
  const int colBase = by * 128;
  const int rs = tid >> 2, ks = (tid & 3) * 8;

  float4 pa[4][2]; hv8 pb[2][2];

  auto issueA = [&](int it) {
    const int k0 = it * 32, s = it & 3;
    pa[s][0] = *(const float4*)&A32[(size_t)(rowBase + rs) * 256 + k0 + ks];
    pa[s][1] = *(const float4*)&A32[(size_t)(rowBase + rs) * 256 + k0 + ks + 4];
  };
  auto issueB = [&](int it) {
    const int k0 = it * 32, s = it & 1;
#pragma unroll
    for (int p = 0; p < 2; ++p)
      pb[s][p] = *(const hv8*)&Bt[(size_t)(colBase + p * 64 + rs) * 256 + k0 + ks];
  };

  // Preamble in need order (A 4-deep, B 2-deep)
  issueA(0); issueB(0); issueA(1); issueB(1); issueA(2); issueA(3);

  fv4 acc[4][2] = {};

#pragma unroll
  for (int it = 0; it < 8; ++it) {
    const int sb = it & 1, sa = it & 3;
    {
      const float4 f0 = pa[sa][0], f1 = pa[sa][1];
      const float fa[8] = {f0.x, f0.y, f0.z, f0.w, f1.x, f1.y, f1.z, f1.w};
      hv8 h;
#pragma unroll
      for (int e = 0; e < 8; ++e) h[e] = (_Float16)fa[e];
      *(hv8*)&As[sb][rs * 40 + ks] = h;
    }
#pragma unroll
    for (int p = 0; p < 2; ++p)
      *(hv8*)&Bs[sb][(p * 64 + rs) * 40 + ks] = pb[sb][p];
    if (it + 2 < 8) issueB(it + 2);   // need order: B first,
    if (it + 4 < 8) issueA(it + 4);   // then A (4-deep)
    WAIT_LGKM0();
    RAW_BARRIER();

    hv8 af[4];
#pragma unroll
    for (int i = 0; i < 4; ++i)
      af[i] = *(const hv8*)&As[sb][(i * 16 + l15) * 40 + quad * 8];
#pragma unroll
    for (int j = 0; j < 2; ++j) {
      const hv8 bf = *(const hv8*)&Bs[sb][(wc + j * 16 + l15) * 40 + quad * 8];
#pragma unroll
      for (int i = 0; i < 4; ++i)
        acc[i][j] = __builtin_amdgcn_mfma_f32_16x16x32_f16(af[i], bf, acc[i][j], 0, 0, 0);
    }
  }

#pragma unroll
  for (int j = 0; j < 2; ++j) {
    const int col = colBase + wc + j * 16 + l15;
    const float bj = bias[col];
#pragma unroll
    for (int i = 0; i < 4; ++i)
#pragma unroll
      for (int rg = 0; rg < 4; ++rg) {
        const int row = rowBase + i * 16 + quad * 4 + rg;
        const float v = acc[i][j][rg] + bj;
        const int n = (row >= LEN_IN) ? 1 : 0;
        const int pix = row - n * LEN_IN;
        const int m = col >> 5, d = col & 31;
        Cout[((size_t)(n * 8 + m) * LEN_IN + pix) * 32 + d] = (_Float16)v;
      }
  }
}

// ---------------------------------------------------------------------------
// offs/logits body: oy=0,1 -> offset coords (f16-split, 3 MFMAs);
// oy=2 -> logits (1 MFMA). A pipeline 4-deep.
// Carve: Ash=sh[0..2560), Asl=sh[2560..5120), Bs=sh[5120..15360).
// ---------------------------------------------------------------------------
__device__ __forceinline__ void offs_body(
    const float* __restrict__ A, const _Float16* __restrict__ B2,
    const float* __restrict__ boff, const float* __restrict__ ba,
    const float* __restrict__ refpts,
    float* __restrict__ C, _Float16* __restrict__ logits16,
    _Float16* sh, int bx, int oy, int tid)
{
  _Float16* Ash = sh;
  _Float16* Asl = sh + 2560;
  _Float16* Bs  = sh + 5120;   // offs: rows 0-127 hi, 128-255 lo. logits: rows 0-127.

  const bool offs = (oy < 2);
  const int np = offs ? 4 : 2;
  const int lane = tid & 63, wave = tid >> 6;
  const int l15 = lane & 15, quad = lane >> 4;
  const int wc = wave * 32;
  const int rowBase = bx * 64;
  const int colBase = offs ? oy * 128 : 0;
  const int rs = tid >> 2, ks = (tid & 3) * 8;

  float4 pa[4][2]; hv8 pb[2][4];

  auto issueA = [&](int it) {
    const int k0 = it * 32, s = it & 3;
    pa[s][0] = *(const float4*)&A[(size_t)(rowBase + rs) * 256 + k0 + ks];
    pa[s][1] = *(const float4*)&A[(size_t)(rowBase + rs) * 256 + k0 + ks + 4];
  };
  auto issueB = [&](int it) {
    const int k0 = it * 32, s = it & 1;
#pragma unroll
    for (int p = 0; p < 4; ++p) {
      if (p >= np) break;
      const int grow = offs
          ? ((p < 2) ? (colBase + p * 64 + rs) : (256 + colBase + (p - 2) * 64 + rs))
          : (512 + p * 64 + rs);
      pb[s][p] = *(const hv8*)&B2[(size_t)grow * 256 + k0 + ks];
    }
  };

  issueA(0); issueB(0); issueA(1); issueB(1); issueA(2); issueA(3);

  fv4 acc[4][2] = {};

#pragma unroll
  for (int it = 0; it < 8; ++it) {
    const int sa = it & 3, s2 = it & 1;
    {
      const float4 f0 = pa[sa][0], f1 = pa[sa][1];
      const float fa[8] = {f0.x, f0.y, f0.z, f0.w, f1.x, f1.y, f1.z, f1.w};
      hv8 hh, ll;
#pragma unroll
      for (int e = 0; e < 8; ++e) {
        hh[e] = (_Float16)fa[e];
        ll[e] = (_Float16)(fa[e] - (float)hh[e]);
      }
      *(hv8*)&Ash[rs * 40 + ks] = hh;
      if (offs) *(hv8*)&Asl[rs * 40 + ks] = ll;
    }
#pragma unroll
    for (int p = 0; p < 4; ++p) {
      if (p >= np) break;
      *(hv8*)&Bs[(p * 64 + rs) * 40 + ks] = pb[s2][p];
    }
    if (it + 2 < 8) issueB(it + 2);
    if (it + 4 < 8) issueA(it + 4);
    WAIT_LGKM0();
    RAW_BARRIER();

    hv8 ah[4];
#pragma unroll
    for (int i = 0; i < 4; ++i)
      ah[i] = *(const hv8*)&Ash[(i * 16 + l15) * 40 + quad * 8];

    if (offs) {
      hv8 al[4];
#pragma unroll
      for (int i = 0; i < 4; ++i)
        al[i] = *(const hv8*)&Asl[(i * 16 + l15) * 40 + quad * 8];
#pragma unroll
      for (int j = 0; j < 2; ++j) {
        const hv8 bh = *(const hv8*)&Bs[(wc + j * 16 + l15) * 40 + quad * 8];
        const hv8 bl = *(const hv8*)&Bs[(128 + wc + j * 16 + l15) * 40 + quad * 8];
#pragma unroll
        for (int i = 0; i < 4; ++i) {
          acc[i][j] = __builtin_amdgcn_mfma_f32_16x16x32_f16(ah[i], bh, acc[i][j], 0, 0, 0);
          acc[i][j] = __builtin_amdgcn_mfma_f32_16x16x32_f16(ah[i], bl, acc[i][j], 0, 0, 0);
          acc[i][j] = __builtin_amdgcn_mfma_f32_16x16x32_f16(al[i], bh, acc[i][j], 0, 0, 0);
        }
      }
    } else {
#pragma unroll
      for (int j = 0; j < 2; ++j) {
        const hv8 bh = *(const hv8*)&Bs[(wc + j * 16 + l15) * 40 + quad * 8];
#pragma unroll
        for (int i = 0; i < 4; ++i)
          acc[i][j] = __builtin_amdgcn_mfma_f32_16x16x32_f16(ah[i], bh, acc[i][j], 0, 0, 0);
      }
    }
    WAIT_LGKM0();   // frag reads done before next iter overwrites (single buf)
    RAW_BARRIER();
  }

  if (offs) {
#pragma unroll
    for (int j = 0; j < 2; ++j) {
      const int c = colBase + wc + j * 16 + l15;
      const int xy = c & 1, l = (c >> 3) & 3;
      const float Wl = (float)(128 >> l);
      const float bj = boff[c];
#pragma unroll
      for (int i = 0; i < 4; ++i)
#pragma unroll
        for (int rg = 0; rg < 4; ++rg) {
          const int row = rowBase + i * 16 + quad * 4 + rg;
          const float ref = refpts[(size_t)row * 8 + l * 2 + xy];
          C[(size_t)row * 256 + c] = (acc[i][j][rg] + bj + ref) * Wl - 0.5f;
        }
    }
  } else {
#pragma unroll
    for (int j = 0; j < 2; ++j) {
      const int col = wc + j * 16 + l15;
      const float bj = ba[col];
#pragma unroll
      for (int i = 0; i < 4; ++i)
#pragma unroll
        for (int rg = 0; rg < 4; ++rg) {
          const int row = rowBase + i * 16 + quad * 4 + rg;
          logits16[(size_t)row * 128 + col] = (_Float16)(acc[i][j][rg] + bj);
        }
    }
  }
}

// ---------------------------------------------------------------------------
// MERGED front dispatch: offs blocks 0..2039, value blocks 2040..3399.
// Same 30720 B LDS carve per body.
// ---------------------------------------------------------------------------
__global__ __launch_bounds__(256) void gemm_front(
    const float* __restrict__ flatten, const _Float16* __restrict__ WvT,
    const float* __restrict__ bv, _Float16* __restrict__ value16,
    const float* __restrict__ query, const _Float16* __restrict__ B2,
    const float* __restrict__ boff, const float* __restrict__ ba,
    const float* __restrict__ refpts,
    float* __restrict__ coords, _Float16* __restrict__ logits16)
{
  __shared__ _Float16 sh[15360];   // 30720 B, carved per body
  const int id = blockIdx.x, tid = threadIdx.x;
  if (id < 2040) {
    offs_body(query, B2, boff, ba, refpts, coords, logits16, sh,
              id % 680, id / 680, tid);
  } else {
    const int vid = id - 2040;
    value_body(flatten, WvT, bv, value16, sh, vid % 680, vid / 680, tid);
  }
}

// ---------------------------------------------------------------------------
// Final GEMM — m97-pattern glds rewrite: A and B (both f16) staged DIRECT
// global->LDS via global_load_lds (no staging VGPRs, no reg->LDS hop).
// Unpadded stride-32 rows (glds dest must be wave-uniform base + lane*16:
// lane l -> row w*16+(l>>2), halves (l&3)*8 => byte off 16*l, linear).
// Double-buffered; stage(it+1) overlaps ds_read+MFMA(it); full drain +
// barrier per iter (m97-accepted). LDS 24576 B -> 6 blocks/CU; VGPR ~64
// -> co-residency cap rises ~20 -> 24 waves/CU.
// ---------------------------------------------------------------------------
__global__ __launch_bounds__(256) void gemm_final(
    const _Float16* __restrict__ A16, const _Float16* __restrict__ Bt,
    const float* __restrict__ bias, float* __restrict__ Cout)
{
  __shared__ _Float16 As[2][64 * 32];    // 4096 B each
  __shared__ _Float16 Bs[2][128 * 32];   // 8192 B each -> total 24576 B

  const int tid = threadIdx.x, lane = tid & 63, wave = tid >> 6;
  const int l15 = lane & 15, quad = lane >> 4;
  const int wc = wave * 32;
  const int rowBase = blockIdx.x * 64;
  const int colBase = blockIdx.y * 128;
  const int lrow = lane >> 2, lks = (lane & 3) * 8;

  // Per-wave staging: A = 1 glds (16 rows), B = 2 glds (2 x 16 rows).
  auto stageAB = [&](int it) {
    const int sb = it & 1, k0 = it * 32;
    glds16(&A16[(size_t)(rowBase + wave * 16 + lrow) * 256 + k0 + lks],
           &As[sb][(wave * 16) * 32]);
#pragma unroll
    for (int p = 0; p < 2; ++p)
      glds16(&Bt[(size_t)(colBase + wave * 32 + p * 16 + lrow) * 256 + k0 + lks],
             &Bs[sb][(wave * 32 + p * 16) * 32]);
  };

  stageAB(0);
  __builtin_amdgcn_s_waitcnt(0);
  RAW_BARRIER();

  fv4 acc[4][2] = {};

#pragma unroll
  for (int it = 0; it < 8; ++it) {
    const int sb = it & 1;
    if (it + 1 < 8) stageAB(it + 1);   // overlaps this iter's reads+MFMA

    hv8 af[4];
#pragma unroll
    for (int i = 0; i < 4; ++i)
      af[i] = *(const hv8*)&As[sb][(i * 16 + l15) * 32 + quad * 8];
#pragma unroll
    for (int j = 0; j < 2; ++j) {
      const hv8 bf = *(const hv8*)&Bs[sb][(wc + j * 16 + l15) * 32 + quad * 8];
#pragma unroll
      for (int i = 0; i < 4; ++i)
        acc[i][j] = __builtin_amdgcn_mfma_f32_16x16x32_f16(af[i], bf, acc[i][j], 0, 0, 0);
    }

    __builtin_amdgcn_s_waitcnt(0);   // stage(it+1) landed; reads of sb done
    RAW_BARRIER();                   // before anyone overwrites sb at it+2
  }

#pragma unroll
  for (int j = 0; j < 2; ++j) {
    const int col = colBase + wc + j * 16 + l15;
    const float bj = bias[col];
#pragma unroll
    for (int i = 0; i < 4; ++i)
#pragma unroll
      for (int rg = 0; rg < 4; ++rg) {
        const int row = rowBase + i * 16 + quad * 4 + rg;
        Cout[(size_t)row * 256 + col] = acc[i][j][rg] + bj;
      }
  }
}

// ---------------------------------------------------------------------------
// Sampler (R8: fdot2 corner-pair accumulate; gather-latency-bound ~70 us).
// ---------------------------------------------------------------------------
__global__ __launch_bounds__(256, 8) void sample_kernel(
    const _Float16* __restrict__ value16,  // head planes
    const float* __restrict__ coords,      // (B, LQ, 256) pixel coords
    const _Float16* __restrict__ logits16, // (B, LQ, 128)
    _Float16* __restrict__ outp16)         // (B, LQ, 256)
{
  __shared__ unsigned s_pair[4096];
  __shared__ float    s_attn[1024];

  const int tid = threadIdx.x;
  const int qBase = blockIdx.x * 8;

  if (tid < 64) {   // softmax per (q,m) over 16
    const hv8* lp = (const hv8*)&logits16[(size_t)(qBase + (tid >> 3)) * 128 + (tid & 7) * 16];
    const hv8 w0 = lp[0], w1 = lp[1];
    float w[16];
#pragma unroll
    for (int e = 0; e < 8; ++e) { w[e] = (float)w0[e]; w[8 + e] = (float)w1[e]; }
    float mx = w[0];
#pragma unroll
    for (int i = 1; i < 16; ++i) mx = fmaxf(mx, w[i]);
    float sum = 0.f;
#pragma unroll
    for (int i = 0; i < 16; ++i) { w[i] = expf(w[i] - mx); sum += w[i]; }
    const float inv = 1.f / sum;
#pragma unroll
    for (int p = 0; p < 16; ++p) s_attn[p * 64 + tid] = w[p] * inv;
  }
  __syncthreads();

#pragma unroll
  for (int k = 0; k < 4; ++k) {
    const int i = tid + 256 * k;
    const int p = i >> 6, q = (i >> 3) & 7, m = i & 7;
    const int l = p >> 2, pp = p & 3;
    const int qg = qBase + q;
    const float2 of = *(const float2*)&coords[(size_t)qg * 256 + ((m * 4 + l) * 4 + pp) * 2];
    const float aw = s_attn[i];
    const int W = 128 >> l;
    const int st = (l == 0) ? 0 : (l == 1) ? 16384 : (l == 2) ? 20480 : 21504;
    const float xf = floorf(of.x), yf = floorf(of.y);
    const int x0 = (int)xf, y0 = (int)yf;
    const float wx = of.x - xf, wy = of.y - yf;
    uint4 rec;
    unsigned* rp = &rec.x;
#pragma unroll
    for (int c = 0; c < 4; ++c) {
      const int dx = c & 1, dy = c >> 1;
      const int xi = x0 + dx, yi = y0 + dy;
      const bool valid = (xi >= 0) & (xi < W) & (yi >= 0) & (yi < W);
      const float w = (dx ? wx : 1.f - wx) * (dy ? wy : 1.f - wy) * aw;
      union { _Float16 h; unsigned short s; } pk;
      pk.h = (_Float16)w;
      const unsigned idx = (unsigned)(st + yi * W + xi);
      rp[c] = valid ? (idx | ((unsigned)pk.s << 16)) : 0u;
    }
    *(uint4*)&s_pair[i * 4] = rec;
  }
  __syncthreads();

  const int wave = tid >> 6, lane = tid & 63;
  const int qloc = wave * 2 + (lane >> 5);
  const int sub = lane & 31, m = sub >> 2, j = sub & 3;
  const int qg = qBase + qloc;
  const int n = (qg >= LEN_IN) ? 1 : 0;
  const char* base = (const char*)value16 + (size_t)(n * 8 + m) * LEN_IN * 64 + j * 16;
  const int lb = qloc * 8 + m;

  float acc8[8] = {0.f, 0.f, 0.f, 0.f, 0.f, 0.f, 0.f, 0.f};

  // Corner-pair accumulate: acc8[e] += wA*vA[e] + wB*vB[e] via fdot2.
  auto pair_acc = [&](unsigned uA, unsigned uB) {
    const hv8 vA = *(const hv8*)(base + (size_t)(uA & 32767u) * 64);
    const hv8 vB = *(const hv8*)(base + (size_t)(uB & 32767u) * 64);
    const unsigned wp = __builtin_amdgcn_perm(uB, uA, 0x07060302u);
    union { unsigned u; hv2 h; } w2; w2.u = wp;
    const unsigned* va = (const unsigned*)&vA;
    const unsigned* vb = (const unsigned*)&vB;
#pragma unroll
    for (int r = 0; r < 4; ++r) {
      union { unsigned u; hv2 h; } lo, hi;
      lo.u = __builtin_amdgcn_perm(vb[r], va[r], 0x05040100u);
      hi.u = __builtin_amdgcn_perm(vb[r], va[r], 0x07060302u);
      acc8[2 * r]     = __builtin_amdgcn_fdot2(w2.h, lo.h, acc8[2 * r],     false);
      acc8[2 * r + 1] = __builtin_amdgcn_fdot2(w2.h, hi.h, acc8[2 * r + 1], false);
    }
  };

#pragma unroll 4
  for (int p = 0; p < 16; ++p) {
    const uint4 u4 = *(const uint4*)&s_pair[(p * 64 + lb) * 4];
    pair_acc(u4.x, u4.y);
    pair_acc(u4.z, u4.w);
  }

  hv8 o;
#pragma unroll
  for (int e = 0; e < 8; ++e) o[e] = (_Float16)acc8[e];
  *(hv8*)&outp16[(size_t)qg * 256 + m * 32 + j * 8] = o;
}

// ---------------------------------------------------------------------------
extern "C" void kernel_launch(void* const* d_in, const int* in_sizes, int n_in,
                              void* d_out, int out_size, void* d_ws, size_t ws_size,
                              hipStream_t stream) {
  const float* query   = (const float*)d_in[0];
  const float* refpts  = (const float*)d_in[1];
  const float* flatten = (const float*)d_in[2];
  const float* Wv   = (const float*)d_in[5];
  const float* bv   = (const float*)d_in[6];
  const float* Woff = (const float*)d_in[7];
  const float* boff = (const float*)d_in[8];
  const float* Wa   = (const float*)d_in[9];
  const float* ba   = (const float*)d_in[10];
  const float* Wo   = (const float*)d_in[11];
  const float* bo   = (const float*)d_in[12];
  float* out = (float*)d_out;

  // Workspace (~101 MB): value16 | coords | logits16 | outp16 | weights
  const size_t NE = (size_t)MROWS * 256;            // 11,141,120
  _Float16* value16  = (_Float16*)d_ws;             // NE halves (head planes)
  float*    coords   = (float*)(value16 + NE);      // NE floats
  _Float16* logits16 = (_Float16*)(coords + NE);    // NE/2 halves
  _Float16* outp16   = logits16 + NE / 2;           // NE halves
  _Float16* WvT      = outp16 + NE;                 // 256*256
  _Float16* WoffT2   = WvT + 256 * 256;             // 512*256 (hi|lo)
  _Float16* WaT      = WoffT2 + 512 * 256;          // 128*256 (contig after WoffT2!)
  _Float16* WoT      = WaT + 128 * 256;             // 256*256

  const dim3 blk(256);
  const int mtiles = MROWS / 64;   // 680

  cvt_weights<<<dim3(56), blk, 0, stream>>>(Wv, Woff, Wa, Wo, WvT, WoffT2, WaT, WoT);

  // MERGED (offs first): coords/logits blocks 0..2039, value blocks 2040..3399
  gemm_front<<<dim3(3400), blk, 0, stream>>>(flatten, WvT, bv, value16,
                                             query, WoffT2, boff, ba, refpts,
                                             coords, logits16);

  // sampling -> out_pre (f16)
  sample_kernel<<<dim3(MROWS / 8), blk, 0, stream>>>(value16, coords, logits16, outp16);

  // out = out_pre @ Wo + bo (fp32 to d_out)
  gemm_final<<<dim3(mtiles, 2), blk, 0, stream>>>(outp16, WoT, bo, out);
}